// Round 1
// 6059.250 us; speedup vs baseline: 1.6433x; 1.6433x over previous
//
#include <hip/hip_runtime.h>
#include <math.h>

// Sizes (fixed by the reference)
#define BB  64
#define SS  128
#define HH  1024
#define EE  1024
#define EMBD 512
#define VV  32000
#define TT  50

// workspace offsets (floats)
#define OFF_H     0
#define OFF_C     65536
#define OFF_PREV  131072
#define OFF_HC    163840
#define OFF_GPART 294912      // 6 x 64x4096
#define OFF_DPART 1867776     // 8 x 64x512
#define OFF_DEC   2129920
#define OFF_QPART 2162688     // 4 x 64x1024 (fallback path only)
#define OFF_TVAL  2424832     // 500 x 64
#define OFF_TIDX  2456832     // 500 x 64 (int)
#define OFF_SYM   2488832
#define OFF_TL    2488896
#define OFF_KEYS  2488960     // 8192 x 1024 (keys path)
#define WS_NEED_KEYS ((size_t)(OFF_KEYS + 8388608) * 4)

// ---------------------------------------------------------------------------
// Generic M=64 tiled f32 GEMM tile: C[64 x 64] += A[64 x K] * B
//  BT=true : B stored [N x K] row-major (we compute A @ B^T)
//  BT=false: B stored [K x N] row-major (we compute A @ B)
// ---------------------------------------------------------------------------
template<bool BT>
__device__ __forceinline__ void gemm_tile(const float* __restrict__ A, int lda,
                                          const float* __restrict__ B, int ldb,
                                          float* __restrict__ C, size_t ldc, int K)
{
    __shared__ __attribute__((aligned(16))) float As[32][68];
    __shared__ __attribute__((aligned(16))) float Bs[32][68];
    int tid = threadIdx.x;
    int tx = tid & 15, ty = tid >> 4;
    float acc[4][4] = {};
    int lr = tid >> 2;
    int lk = (tid & 3) << 3;
    int bk = tid >> 3;
    int bn = (tid & 7) << 3;

    for (int kc = 0; kc < K; kc += 32) {
        float4 a0 = *(const float4*)(A + (size_t)lr * lda + kc + lk);
        float4 a1 = *(const float4*)(A + (size_t)lr * lda + kc + lk + 4);
        As[lk+0][lr] = a0.x; As[lk+1][lr] = a0.y; As[lk+2][lr] = a0.z; As[lk+3][lr] = a0.w;
        As[lk+4][lr] = a1.x; As[lk+5][lr] = a1.y; As[lk+6][lr] = a1.z; As[lk+7][lr] = a1.w;
        if (BT) {
            float4 b0 = *(const float4*)(B + (size_t)lr * ldb + kc + lk);
            float4 b1 = *(const float4*)(B + (size_t)lr * ldb + kc + lk + 4);
            Bs[lk+0][lr] = b0.x; Bs[lk+1][lr] = b0.y; Bs[lk+2][lr] = b0.z; Bs[lk+3][lr] = b0.w;
            Bs[lk+4][lr] = b1.x; Bs[lk+5][lr] = b1.y; Bs[lk+6][lr] = b1.z; Bs[lk+7][lr] = b1.w;
        } else {
            float4 b0 = *(const float4*)(B + (size_t)(kc + bk) * ldb + bn);
            float4 b1 = *(const float4*)(B + (size_t)(kc + bk) * ldb + bn + 4);
            *(float4*)&Bs[bk][bn]     = b0;
            *(float4*)&Bs[bk][bn + 4] = b1;
        }
        __syncthreads();
        #pragma unroll 8
        for (int k = 0; k < 32; ++k) {
            float4 av = *(const float4*)&As[k][ty << 2];
            float4 bv = *(const float4*)&Bs[k][tx << 2];
            float am[4] = {av.x, av.y, av.z, av.w};
            float bm[4] = {bv.x, bv.y, bv.z, bv.w};
            #pragma unroll
            for (int i = 0; i < 4; ++i)
                #pragma unroll
                for (int j = 0; j < 4; ++j)
                    acc[i][j] = fmaf(am[i], bm[j], acc[i][j]);
        }
        __syncthreads();
    }
    #pragma unroll
    for (int i = 0; i < 4; ++i) {
        float4 w = make_float4(acc[i][0], acc[i][1], acc[i][2], acc[i][3]);
        *(float4*)(C + (size_t)((ty << 2) + i) * ldc + (tx << 2)) = w;
    }
}

__global__ __launch_bounds__(256) void k_gemm_bt(const float* __restrict__ A, int lda,
                                                 const float* __restrict__ B, int ldb,
                                                 float* __restrict__ C, long long ldc,
                                                 int KC, long long partStride)
{
    int n0 = blockIdx.x << 6;
    int k0 = blockIdx.y * KC;
    gemm_tile<true>(A + k0, lda, B + (size_t)n0 * ldb + k0, ldb,
                    C + (size_t)blockIdx.y * partStride + n0, (size_t)ldc, KC);
}

__global__ __launch_bounds__(256) void k_gemm_bn(const float* __restrict__ A, int lda,
                                                 const float* __restrict__ B, int ldb,
                                                 float* __restrict__ C, long long ldc,
                                                 int KC, long long partStride)
{
    int n0 = blockIdx.x << 6;
    int k0 = blockIdx.y * KC;
    gemm_tile<false>(A + k0, lda, B + (size_t)k0 * ldb + n0, ldb,
                     C + (size_t)blockIdx.y * partStride + n0, (size_t)ldc, KC);
}

// keys[b*S+s, h] = sum_e enc[b,s,e] * Wap[h,e]   (one-time, M=8192)
__global__ __launch_bounds__(256) void k_keys(const float* __restrict__ enc,
                                              const float* __restrict__ Wap,
                                              float* __restrict__ keys)
{
    int n0 = blockIdx.x << 6;     // 16 tiles over H
    int m0 = blockIdx.y << 6;     // 128 tiles over B*S
    gemm_tile<true>(enc + (size_t)m0 * EE, EE, Wap + (size_t)n0 * EE, EE,
                    keys + (size_t)m0 * HH + n0, (size_t)HH, EE);
}

// gates = prev @ W_ih^T + h @ W_hh^T  (6-way K split of 256 -> 384 blocks)
__global__ __launch_bounds__(256) void k_gates(const float* __restrict__ prev,
                                               const float* __restrict__ h,
                                               const float* __restrict__ Wih,
                                               const float* __restrict__ Whh,
                                               float* __restrict__ part)
{
    int n0 = blockIdx.x << 6;
    int ks = blockIdx.y;          // 0..5
    const float* A; const float* Bp; int lda, ldb;
    if (ks < 2) { A = prev + ks * 256;      lda = EMBD; Bp = Wih + (size_t)n0 * EMBD + ks * 256;       ldb = EMBD; }
    else        { A = h + (ks - 2) * 256;   lda = HH;   Bp = Whh + (size_t)n0 * HH + (ks - 2) * 256;   ldb = HH;   }
    gemm_tile<true>(A, lda, Bp, ldb, part + (size_t)ks * 262144 + n0, 4096, 256);
}

// reduce 6 gate partials + bias, LSTM cell update; writes h, c, and h-half of hc
__global__ void k_lstm(const float* __restrict__ part, const float* __restrict__ bias,
                       float* __restrict__ h, float* __restrict__ c, float* __restrict__ hc)
{
    int idx = blockIdx.x * 256 + threadIdx.x;     // 65536 = 64 x 1024
    int b = idx >> 10, j = idx & 1023;
    size_t base = (size_t)b * 4096;
    #define GATE(col) (part[base + (col)] + part[base + (col) + 262144] + part[base + (col) + 524288] \
                     + part[base + (col) + 786432] + part[base + (col) + 1048576] + part[base + (col) + 1310720] \
                     + bias[(col)])
    float gi = GATE(j);
    float gf = GATE(j + 1024);
    float gg = GATE(j + 2048);
    float go = GATE(j + 3072);
    #undef GATE
    float si = 1.f / (1.f + expf(-gi));
    float sf = 1.f / (1.f + expf(-gf));
    float so = 1.f / (1.f + expf(-go));
    float cn = sf * c[idx] + si * tanhf(gg);
    float hn = so * tanhf(cn);
    c[idx] = cn;
    h[idx] = hn;
    hc[(size_t)b * 2048 + j] = hn;
}

// attention (keys path): scores = keys . h, masked softmax, c_t = alpha . enc
// 64 blocks x 1024 threads (16 waves) for latency hiding
__global__ __launch_bounds__(1024) void k_attn(const float* __restrict__ keys,
                                               const float* __restrict__ enc,
                                               const int* __restrict__ enc_len,
                                               const float* __restrict__ h,
                                               float* __restrict__ hc)
{
    __shared__ float hs[1024];
    __shared__ float sc[128];
    __shared__ float4 red[3][256];
    int b = blockIdx.x, tid = threadIdx.x;
    hs[tid] = h[(size_t)b * 1024 + tid];
    __syncthreads();
    int lane = tid & 63, w = tid >> 6;      // 16 waves
    const float* kb = keys + (size_t)b * SS * HH;
    for (int s = w; s < 128; s += 16) {
        const float* kr = kb + (size_t)s * 1024;
        float acc = 0.f;
        #pragma unroll
        for (int i = 0; i < 16; ++i) acc = fmaf(kr[i * 64 + lane], hs[i * 64 + lane], acc);
        #pragma unroll
        for (int off = 32; off; off >>= 1) acc += __shfl_xor(acc, off, 64);
        if (lane == 0) sc[s] = acc;
    }
    __syncthreads();
    int len = enc_len[b];
    if (tid < 64) {
        float a  = (tid < len)      ? sc[tid]      : -1e9f;
        float a2 = (tid + 64 < len) ? sc[tid + 64] : -1e9f;
        float m = fmaxf(a, a2);
        #pragma unroll
        for (int off = 32; off; off >>= 1) m = fmaxf(m, __shfl_xor(m, off, 64));
        float ea = expf(a - m), ea2 = expf(a2 - m);
        float ssum = ea + ea2;
        #pragma unroll
        for (int off = 32; off; off >>= 1) ssum += __shfl_xor(ssum, off, 64);
        sc[tid] = ea / ssum; sc[tid + 64] = ea2 / ssum;
    }
    __syncthreads();
    // ctx: 4 groups of 256 threads, each group 32 s-rows, float4 over E
    int g = tid >> 8, t2 = tid & 255;
    const float* eb = enc + (size_t)b * SS * EE;
    float4 a4 = make_float4(0.f, 0.f, 0.f, 0.f);
    for (int s = g * 32; s < g * 32 + 32; ++s) {
        float al = sc[s];
        float4 e = *(const float4*)(eb + (size_t)s * 1024 + t2 * 4);
        a4.x = fmaf(al, e.x, a4.x); a4.y = fmaf(al, e.y, a4.y);
        a4.z = fmaf(al, e.z, a4.z); a4.w = fmaf(al, e.w, a4.w);
    }
    if (g) red[g - 1][t2] = a4;
    __syncthreads();
    if (g == 0) {
        float4 r1 = red[0][t2], r2 = red[1][t2], r3 = red[2][t2];
        a4.x += r1.x + r2.x + r3.x; a4.y += r1.y + r2.y + r3.y;
        a4.z += r1.z + r2.z + r3.z; a4.w += r1.w + r2.w + r3.w;
        *(float4*)(hc + (size_t)b * 2048 + 1024 + t2 * 4) = a4;
    }
}

// fallback attention (qpart path, original)
__global__ __launch_bounds__(256) void k_attn_fb(const float* __restrict__ qpart,
                                                 const float* __restrict__ enc,
                                                 const int* __restrict__ enc_len,
                                                 float* __restrict__ hc)
{
    __shared__ float qs[1024];
    __shared__ float sc[128];
    int b = blockIdx.x, tid = threadIdx.x;
    for (int e = tid; e < 1024; e += 256) {
        size_t o = (size_t)b * 1024 + e;
        qs[e] = qpart[o] + qpart[o + 65536] + qpart[o + 131072] + qpart[o + 196608];
    }
    __syncthreads();
    int lane = tid & 63, w = tid >> 6;
    const float* eb = enc + (size_t)b * SS * EE;
    for (int s = w; s < 128; s += 4) {
        const float* er = eb + (size_t)s * 1024;
        float acc = 0.f;
        #pragma unroll
        for (int i = 0; i < 16; ++i) acc = fmaf(er[i * 64 + lane], qs[i * 64 + lane], acc);
        #pragma unroll
        for (int off = 32; off; off >>= 1) acc += __shfl_xor(acc, off, 64);
        if (lane == 0) sc[s] = acc;
    }
    __syncthreads();
    int len = enc_len[b];
    if (tid < 64) {
        float a  = (tid < len)      ? sc[tid]      : -1e9f;
        float a2 = (tid + 64 < len) ? sc[tid + 64] : -1e9f;
        float m = fmaxf(a, a2);
        #pragma unroll
        for (int off = 32; off; off >>= 1) m = fmaxf(m, __shfl_xor(m, off, 64));
        float ea = expf(a - m), ea2 = expf(a2 - m);
        float ssum = ea + ea2;
        #pragma unroll
        for (int off = 32; off; off >>= 1) ssum += __shfl_xor(ssum, off, 64);
        sc[tid] = ea / ssum; sc[tid + 64] = ea2 / ssum;
    }
    __syncthreads();
    float acc[4] = {0.f, 0.f, 0.f, 0.f};
    for (int s = 0; s < 128; ++s) {
        float al = sc[s];
        const float* er = eb + (size_t)s * 1024;
        #pragma unroll
        for (int j = 0; j < 4; ++j) acc[j] = fmaf(al, er[tid + j * 256], acc[j]);
    }
    #pragma unroll
    for (int j = 0; j < 4; ++j) hc[(size_t)b * 2048 + 1024 + tid + j * 256] = acc[j];
}

__global__ void k_reduce_dec(const float* __restrict__ part, float* __restrict__ dec)
{
    int i = blockIdx.x * 256 + threadIdx.x;   // 32768
    float s = 0.f;
    #pragma unroll
    for (int p = 0; p < 8; ++p) s += part[p * 32768 + i];
    dec[i] = s;
}

// vocab logits GEMM (64 x 32000, K=512) with fused per-tile row-max epilogue
__global__ __launch_bounds__(256) void k_vocab(const float* __restrict__ A,
                                               const float* __restrict__ B,
                                               float* __restrict__ out, int t,
                                               float* __restrict__ tval, int* __restrict__ tidx)
{
    __shared__ __attribute__((aligned(16))) float As[32][68];
    __shared__ __attribute__((aligned(16))) float Bs[32][68];
    int n0 = blockIdx.x << 6;
    const float* Bp = B + (size_t)n0 * EMBD;
    int tid = threadIdx.x;
    int tx = tid & 15, ty = tid >> 4;
    float acc[4][4] = {};
    int lr = tid >> 2;
    int lk = (tid & 3) << 3;

    for (int kc = 0; kc < EMBD; kc += 32) {
        float4 a0 = *(const float4*)(A + (size_t)lr * EMBD + kc + lk);
        float4 a1 = *(const float4*)(A + (size_t)lr * EMBD + kc + lk + 4);
        As[lk+0][lr] = a0.x; As[lk+1][lr] = a0.y; As[lk+2][lr] = a0.z; As[lk+3][lr] = a0.w;
        As[lk+4][lr] = a1.x; As[lk+5][lr] = a1.y; As[lk+6][lr] = a1.z; As[lk+7][lr] = a1.w;
        float4 b0 = *(const float4*)(Bp + (size_t)lr * EMBD + kc + lk);
        float4 b1 = *(const float4*)(Bp + (size_t)lr * EMBD + kc + lk + 4);
        Bs[lk+0][lr] = b0.x; Bs[lk+1][lr] = b0.y; Bs[lk+2][lr] = b0.z; Bs[lk+3][lr] = b0.w;
        Bs[lk+4][lr] = b1.x; Bs[lk+5][lr] = b1.y; Bs[lk+6][lr] = b1.z; Bs[lk+7][lr] = b1.w;
        __syncthreads();
        #pragma unroll 8
        for (int k = 0; k < 32; ++k) {
            float4 av = *(const float4*)&As[k][ty << 2];
            float4 bv = *(const float4*)&Bs[k][tx << 2];
            float am[4] = {av.x, av.y, av.z, av.w};
            float bm[4] = {bv.x, bv.y, bv.z, bv.w};
            #pragma unroll
            for (int i = 0; i < 4; ++i)
                #pragma unroll
                for (int j = 0; j < 4; ++j)
                    acc[i][j] = fmaf(am[i], bm[j], acc[i][j]);
        }
        __syncthreads();
    }
    size_t ldc = (size_t)TT * VV;
    float* Cb = out + (size_t)t * VV + n0;
    #pragma unroll
    for (int i = 0; i < 4; ++i) {
        float4 w = make_float4(acc[i][0], acc[i][1], acc[i][2], acc[i][3]);
        *(float4*)(Cb + (size_t)((ty << 2) + i) * ldc + (tx << 2)) = w;
    }
    // per-tile (row-max, lowest-index) -> tval/tidx[tile*64 + row]
    #pragma unroll
    for (int i = 0; i < 4; ++i) {
        float v = acc[i][0]; int jx = 0;
        if (acc[i][1] > v) { v = acc[i][1]; jx = 1; }
        if (acc[i][2] > v) { v = acc[i][2]; jx = 2; }
        if (acc[i][3] > v) { v = acc[i][3]; jx = 3; }
        int gi = n0 + (tx << 2) + jx;
        #pragma unroll
        for (int mk = 1; mk < 16; mk <<= 1) {
            float ov = __shfl_xor(v, mk, 64);
            int   oi = __shfl_xor(gi, mk, 64);
            if (ov > v || (ov == v && oi < gi)) { v = ov; gi = oi; }
        }
        if (tx == 0) {
            tval[blockIdx.x * 64 + (ty << 2) + i] = v;
            tidx[blockIdx.x * 64 + (ty << 2) + i] = gi;
        }
    }
}

// reduce 500 tile maxima per batch row, set prev embedding + sym + tl
__global__ __launch_bounds__(256) void k_argmax2(const float* __restrict__ tval,
                                                 const int* __restrict__ tidx,
                                                 const float* __restrict__ emb,
                                                 float* __restrict__ prev,
                                                 int* __restrict__ sym, int* __restrict__ tl, int t)
{
    __shared__ float bv[256];
    __shared__ int   bi[256];
    int b = blockIdx.x, tid = threadIdx.x;
    float mv = -INFINITY; int mi = 0x7fffffff;
    for (int tile = tid; tile < 500; tile += 256) {
        float v = tval[tile * 64 + b];
        int  ix = tidx[tile * 64 + b];
        if (v > mv || (v == mv && ix < mi)) { mv = v; mi = ix; }
    }
    bv[tid] = mv; bi[tid] = mi;
    __syncthreads();
    for (int s = 128; s; s >>= 1) {
        if (tid < s) {
            float ov = bv[tid + s]; int oi = bi[tid + s];
            if (ov > bv[tid] || (ov == bv[tid] && oi < bi[tid])) { bv[tid] = ov; bi[tid] = oi; }
        }
        __syncthreads();
    }
    int best = bi[0];
    if (tid == 0) { sym[b] = best; if (best == 1) tl[b] = t + 1; }
    for (int e = tid; e < 128; e += 256)
        ((float4*)(prev + (size_t)b * EMBD))[e] = ((const float4*)(emb + (size_t)best * EMBD))[e];
}

__global__ void k_tl(const int* __restrict__ sym, const int* __restrict__ tl, float* __restrict__ out_tl)
{
    int b = threadIdx.x;
    out_tl[b] = (float)((sym[b] == 1) ? tl[b] : TT);
}

// in-place log_softmax per (b,t) row of 32000 — online max+sum (2 passes)
__global__ __launch_bounds__(256) void k_logsm(float* __restrict__ out)
{
    __shared__ float rm[256], rs[256];
    size_t base = (size_t)blockIdx.x * VV;
    int tid = threadIdx.x;
    float m = -INFINITY, s = 0.f;
    for (int v = tid; v < VV; v += 256) {
        float x = out[base + v];
        if (x > m) { s = s * expf(m - x) + 1.f; m = x; }
        else       { s += expf(x - m); }
    }
    rm[tid] = m; rs[tid] = s;
    __syncthreads();
    for (int st = 128; st; st >>= 1) {
        if (tid < st) {
            float m2 = rm[tid + st], s2 = rs[tid + st];
            float M = fmaxf(rm[tid], m2);
            rs[tid] = rs[tid] * expf(rm[tid] - M) + s2 * expf(m2 - M);
            rm[tid] = M;
        }
        __syncthreads();
    }
    float lse = rm[0] + logf(rs[0]);
    for (int v = tid; v < VV; v += 256) out[base + v] -= lse;
}

__global__ void k_init(const float* __restrict__ dis, float* __restrict__ h, float* __restrict__ c,
                       float* __restrict__ prev, int* __restrict__ tl)
{
    int idx = blockIdx.x * 256 + threadIdx.x;   // 65536
    h[idx] = dis[idx];
    c[idx] = dis[65536 + idx];
    if (idx < 32768) prev[idx] = 0.f;
    if (idx < 64) tl[idx] = 0;
}

extern "C" void kernel_launch(void* const* d_in, const int* in_sizes, int n_in,
                              void* d_out, int out_size, void* d_ws, size_t ws_size,
                              hipStream_t stream)
{
    const float* dis  = (const float*)d_in[0];
    const float* enc  = (const float*)d_in[1];
    const int*   elen = (const int*)  d_in[2];
    const float* Wih  = (const float*)d_in[4];
    const float* Whh  = (const float*)d_in[5];
    const float* bl   = (const float*)d_in[6];
    const float* Wap  = (const float*)d_in[7];
    const float* Wout = (const float*)d_in[8];
    const float* Wvoc = (const float*)d_in[9];
    const float* emb  = (const float*)d_in[10];
    float* out = (float*)d_out;
    float* ws  = (float*)d_ws;

    float* h     = ws + OFF_H;
    float* c     = ws + OFF_C;
    float* prev  = ws + OFF_PREV;
    float* hc    = ws + OFF_HC;
    float* gpart = ws + OFF_GPART;
    float* dpart = ws + OFF_DPART;
    float* dec   = ws + OFF_DEC;
    float* qpart = ws + OFF_QPART;
    float* tval  = ws + OFF_TVAL;
    int*   tidx  = (int*)(ws + OFF_TIDX);
    int*   sym   = (int*)(ws + OFF_SYM);
    int*   tl    = (int*)(ws + OFF_TL);
    float* keys  = ws + OFF_KEYS;

    const bool use_keys = ws_size >= WS_NEED_KEYS;

    k_init<<<256, 256, 0, stream>>>(dis, h, c, prev, tl);
    if (use_keys)
        k_keys<<<dim3(16, 128), 256, 0, stream>>>(enc, Wap, keys);

    for (int t = 0; t < TT; ++t) {
        k_gates<<<dim3(64, 6), 256, 0, stream>>>(prev, h, Wih, Whh, gpart);
        k_lstm<<<256, 256, 0, stream>>>(gpart, bl, h, c, hc);
        if (use_keys) {
            k_attn<<<64, 1024, 0, stream>>>(keys, enc, elen, h, hc);
        } else {
            k_gemm_bn<<<dim3(16, 4), 256, 0, stream>>>(h, HH, Wap, EE, qpart, EE, 256, 65536);
            k_attn_fb<<<64, 256, 0, stream>>>(qpart, enc, elen, hc);
        }
        k_gemm_bt<<<dim3(8, 8), 256, 0, stream>>>(hc, 2048, Wout, 2048, dpart, 512, 256, 32768);
        k_reduce_dec<<<128, 256, 0, stream>>>(dpart, dec);
        k_vocab<<<500, 256, 0, stream>>>(dec, Wvoc, out, t, tval, tidx);
        k_argmax2<<<64, 256, 0, stream>>>(tval, tidx, emb, prev, sym, tl, t);
    }

    k_tl<<<1, 64, 0, stream>>>(sym, tl, out + (size_t)BB * TT * VV);
    k_logsm<<<3200, 256, 0, stream>>>(out);
}

// Round 2
// 5712.273 us; speedup vs baseline: 1.7432x; 1.0607x over previous
//
#include <hip/hip_runtime.h>
#include <math.h>

// Sizes (fixed by the reference)
#define BB  64
#define SS  128
#define HH  1024
#define EE  1024
#define EMBD 512
#define VV  32000
#define TT  50
#define NTILE 250          // vocab col tiles of 128

// workspace offsets (floats)
#define OFF_H     0
#define OFF_C     65536
#define OFF_PREV  131072
#define OFF_HC    163840
#define OFF_GPART 294912      // 12 x 64x4096
#define OFF_DPART 3440640     // 16 x 64x512
#define OFF_DEC   3964928
#define OFF_QPART 3997696     // 4 x 64x1024 (fallback path only)
#define OFF_TVAL  4259840     // 250 x 64
#define OFF_TIDX  4276224
#define OFF_TSUM  4292608
#define OFF_LSE   4308992     // 64 x 50
#define OFF_SYM   4313088
#define OFF_TL    4313152
#define OFF_KEYS  4313216     // 8192 x 1024 (keys path)
#define WS_NEED_KEYS ((size_t)(OFF_KEYS + 8388608) * 4)

// ---------------------------------------------------------------------------
// Generic M=64 tiled f32 GEMM tile (4x4 micro): C[64x64] = A[64xK] * B
// ---------------------------------------------------------------------------
template<bool BT>
__device__ __forceinline__ void gemm_tile(const float* __restrict__ A, int lda,
                                          const float* __restrict__ B, int ldb,
                                          float* __restrict__ C, size_t ldc, int K)
{
    __shared__ __attribute__((aligned(16))) float As[32][68];
    __shared__ __attribute__((aligned(16))) float Bs[32][68];
    int tid = threadIdx.x;
    int tx = tid & 15, ty = tid >> 4;
    float acc[4][4] = {};
    int lr = tid >> 2;
    int lk = (tid & 3) << 3;
    int bk = tid >> 3;
    int bn = (tid & 7) << 3;

    for (int kc = 0; kc < K; kc += 32) {
        float4 a0 = *(const float4*)(A + (size_t)lr * lda + kc + lk);
        float4 a1 = *(const float4*)(A + (size_t)lr * lda + kc + lk + 4);
        As[lk+0][lr] = a0.x; As[lk+1][lr] = a0.y; As[lk+2][lr] = a0.z; As[lk+3][lr] = a0.w;
        As[lk+4][lr] = a1.x; As[lk+5][lr] = a1.y; As[lk+6][lr] = a1.z; As[lk+7][lr] = a1.w;
        if (BT) {
            float4 b0 = *(const float4*)(B + (size_t)lr * ldb + kc + lk);
            float4 b1 = *(const float4*)(B + (size_t)lr * ldb + kc + lk + 4);
            Bs[lk+0][lr] = b0.x; Bs[lk+1][lr] = b0.y; Bs[lk+2][lr] = b0.z; Bs[lk+3][lr] = b0.w;
            Bs[lk+4][lr] = b1.x; Bs[lk+5][lr] = b1.y; Bs[lk+6][lr] = b1.z; Bs[lk+7][lr] = b1.w;
        } else {
            float4 b0 = *(const float4*)(B + (size_t)(kc + bk) * ldb + bn);
            float4 b1 = *(const float4*)(B + (size_t)(kc + bk) * ldb + bn + 4);
            *(float4*)&Bs[bk][bn]     = b0;
            *(float4*)&Bs[bk][bn + 4] = b1;
        }
        __syncthreads();
        #pragma unroll 8
        for (int k = 0; k < 32; ++k) {
            float4 av = *(const float4*)&As[k][ty << 2];
            float4 bv = *(const float4*)&Bs[k][tx << 2];
            float am[4] = {av.x, av.y, av.z, av.w};
            float bm[4] = {bv.x, bv.y, bv.z, bv.w};
            #pragma unroll
            for (int i = 0; i < 4; ++i)
                #pragma unroll
                for (int j = 0; j < 4; ++j)
                    acc[i][j] = fmaf(am[i], bm[j], acc[i][j]);
        }
        __syncthreads();
    }
    #pragma unroll
    for (int i = 0; i < 4; ++i) {
        float4 w = make_float4(acc[i][0], acc[i][1], acc[i][2], acc[i][3]);
        *(float4*)(C + (size_t)((ty << 2) + i) * ldc + (tx << 2)) = w;
    }
}

__global__ __launch_bounds__(256) void k_gemm_bt(const float* __restrict__ A, int lda,
                                                 const float* __restrict__ B, int ldb,
                                                 float* __restrict__ C, long long ldc,
                                                 int KC, long long partStride)
{
    int n0 = blockIdx.x << 6;
    int k0 = blockIdx.y * KC;
    gemm_tile<true>(A + k0, lda, B + (size_t)n0 * ldb + k0, ldb,
                    C + (size_t)blockIdx.y * partStride + n0, (size_t)ldc, KC);
}

__global__ __launch_bounds__(256) void k_gemm_bn(const float* __restrict__ A, int lda,
                                                 const float* __restrict__ B, int ldb,
                                                 float* __restrict__ C, long long ldc,
                                                 int KC, long long partStride)
{
    int n0 = blockIdx.x << 6;
    int k0 = blockIdx.y * KC;
    gemm_tile<false>(A + k0, lda, B + (size_t)k0 * ldb + n0, ldb,
                     C + (size_t)blockIdx.y * partStride + n0, (size_t)ldc, KC);
}

// keys = enc @ Wap^T  (one-time): 128x128 tiles, 8x8 micro. grid (8, 64)
__global__ __launch_bounds__(256) void k_keys(const float* __restrict__ enc,
                                              const float* __restrict__ Wap,
                                              float* __restrict__ keys)
{
    __shared__ __attribute__((aligned(16))) float As[32][136];
    __shared__ __attribute__((aligned(16))) float Bs[32][136];
    int n0 = blockIdx.x << 7;
    int m0 = blockIdx.y << 7;
    int tid = threadIdx.x;
    int tx = tid & 15, ty = tid >> 4;
    int lr = tid >> 1, lk = (tid & 1) << 4;
    float acc[8][8] = {};
    const float* Arow = enc + (size_t)(m0 + lr) * EE + lk;
    const float* Brow = Wap + (size_t)(n0 + lr) * EE + lk;

    for (int kc = 0; kc < EE; kc += 32) {
        float4 a0 = *(const float4*)(Arow + kc);
        float4 a1 = *(const float4*)(Arow + kc + 4);
        float4 a2 = *(const float4*)(Arow + kc + 8);
        float4 a3 = *(const float4*)(Arow + kc + 12);
        As[lk+ 0][lr]=a0.x; As[lk+ 1][lr]=a0.y; As[lk+ 2][lr]=a0.z; As[lk+ 3][lr]=a0.w;
        As[lk+ 4][lr]=a1.x; As[lk+ 5][lr]=a1.y; As[lk+ 6][lr]=a1.z; As[lk+ 7][lr]=a1.w;
        As[lk+ 8][lr]=a2.x; As[lk+ 9][lr]=a2.y; As[lk+10][lr]=a2.z; As[lk+11][lr]=a2.w;
        As[lk+12][lr]=a3.x; As[lk+13][lr]=a3.y; As[lk+14][lr]=a3.z; As[lk+15][lr]=a3.w;
        float4 b0 = *(const float4*)(Brow + kc);
        float4 b1 = *(const float4*)(Brow + kc + 4);
        float4 b2 = *(const float4*)(Brow + kc + 8);
        float4 b3 = *(const float4*)(Brow + kc + 12);
        Bs[lk+ 0][lr]=b0.x; Bs[lk+ 1][lr]=b0.y; Bs[lk+ 2][lr]=b0.z; Bs[lk+ 3][lr]=b0.w;
        Bs[lk+ 4][lr]=b1.x; Bs[lk+ 5][lr]=b1.y; Bs[lk+ 6][lr]=b1.z; Bs[lk+ 7][lr]=b1.w;
        Bs[lk+ 8][lr]=b2.x; Bs[lk+ 9][lr]=b2.y; Bs[lk+10][lr]=b2.z; Bs[lk+11][lr]=b2.w;
        Bs[lk+12][lr]=b3.x; Bs[lk+13][lr]=b3.y; Bs[lk+14][lr]=b3.z; Bs[lk+15][lr]=b3.w;
        __syncthreads();
        #pragma unroll 4
        for (int k = 0; k < 32; ++k) {
            float4 av0 = *(const float4*)&As[k][ty << 2];
            float4 av1 = *(const float4*)&As[k][64 + (ty << 2)];
            float4 bv0 = *(const float4*)&Bs[k][tx << 2];
            float4 bv1 = *(const float4*)&Bs[k][64 + (tx << 2)];
            float am[8] = {av0.x,av0.y,av0.z,av0.w, av1.x,av1.y,av1.z,av1.w};
            float bm[8] = {bv0.x,bv0.y,bv0.z,bv0.w, bv1.x,bv1.y,bv1.z,bv1.w};
            #pragma unroll
            for (int i = 0; i < 8; ++i)
                #pragma unroll
                for (int j = 0; j < 8; ++j)
                    acc[i][j] = fmaf(am[i], bm[j], acc[i][j]);
        }
        __syncthreads();
    }
    #pragma unroll
    for (int i = 0; i < 8; ++i) {
        int r = m0 + ((i < 4) ? (ty << 2) + i : 64 + (ty << 2) + (i - 4));
        float* kr = keys + (size_t)r * HH + n0;
        *(float4*)(kr + (tx << 2))      = make_float4(acc[i][0], acc[i][1], acc[i][2], acc[i][3]);
        *(float4*)(kr + 64 + (tx << 2)) = make_float4(acc[i][4], acc[i][5], acc[i][6], acc[i][7]);
    }
}

// gates = prev @ W_ih^T + h @ W_hh^T  (12-way K split of 128 -> 768 blocks)
__global__ __launch_bounds__(256) void k_gates(const float* __restrict__ prev,
                                               const float* __restrict__ h,
                                               const float* __restrict__ Wih,
                                               const float* __restrict__ Whh,
                                               float* __restrict__ part)
{
    int n0 = blockIdx.x << 6;
    int ks = blockIdx.y;          // 0..11
    const float* A; const float* Bp; int lda, ldb;
    if (ks < 4) { A = prev + ks * 128;      lda = EMBD; Bp = Wih + (size_t)n0 * EMBD + ks * 128;       ldb = EMBD; }
    else        { A = h + (ks - 4) * 128;   lda = HH;   Bp = Whh + (size_t)n0 * HH + (ks - 4) * 128;   ldb = HH;   }
    gemm_tile<true>(A, lda, Bp, ldb, part + (size_t)ks * 262144 + n0, 4096, 128);
}

// fused LSTM pointwise + attention. 64 blocks x 1024 threads.
__global__ __launch_bounds__(1024) void k_lstm_attn(const float* __restrict__ part,
                                                    const float* __restrict__ bias,
                                                    const float* __restrict__ keys,
                                                    const float* __restrict__ enc,
                                                    const int* __restrict__ enc_len,
                                                    float* __restrict__ h,
                                                    float* __restrict__ c,
                                                    float* __restrict__ hc)
{
    __shared__ float hs[1024];
    __shared__ float sc[128];
    __shared__ float4 red[3][256];
    int b = blockIdx.x, tid = threadIdx.x;
    // ---- LSTM pointwise: thread tid handles (b, j=tid) ----
    {
        size_t base = (size_t)b * 4096;
        float gi = bias[tid], gf = bias[tid + 1024], gg = bias[tid + 2048], go = bias[tid + 3072];
        #pragma unroll
        for (int p = 0; p < 12; ++p) {
            const float* pp = part + (size_t)p * 3145728 / 12 + base;  // p*262144
            gi += pp[tid]; gf += pp[tid + 1024]; gg += pp[tid + 2048]; go += pp[tid + 3072];
        }
        float si = 1.f / (1.f + expf(-gi));
        float sf = 1.f / (1.f + expf(-gf));
        float so = 1.f / (1.f + expf(-go));
        int idx = b * 1024 + tid;
        float cn = sf * c[idx] + si * tanhf(gg);
        float hn = so * tanhf(cn);
        c[idx] = cn;
        h[idx] = hn;
        hc[(size_t)b * 2048 + tid] = hn;
        hs[tid] = hn;
    }
    __syncthreads();
    // ---- attention: scores = keys . h ----
    int lane = tid & 63, w = tid >> 6;      // 16 waves
    const float* kb = keys + (size_t)b * SS * HH;
    for (int s = w; s < 128; s += 16) {
        const float* kr = kb + (size_t)s * 1024;
        float acc = 0.f;
        #pragma unroll
        for (int i = 0; i < 16; ++i) acc = fmaf(kr[i * 64 + lane], hs[i * 64 + lane], acc);
        #pragma unroll
        for (int off = 32; off; off >>= 1) acc += __shfl_xor(acc, off, 64);
        if (lane == 0) sc[s] = acc;
    }
    __syncthreads();
    int len = enc_len[b];
    if (tid < 64) {
        float a  = (tid < len)      ? sc[tid]      : -1e9f;
        float a2 = (tid + 64 < len) ? sc[tid + 64] : -1e9f;
        float m = fmaxf(a, a2);
        #pragma unroll
        for (int off = 32; off; off >>= 1) m = fmaxf(m, __shfl_xor(m, off, 64));
        float ea = expf(a - m), ea2 = expf(a2 - m);
        float ssum = ea + ea2;
        #pragma unroll
        for (int off = 32; off; off >>= 1) ssum += __shfl_xor(ssum, off, 64);
        sc[tid] = ea / ssum; sc[tid + 64] = ea2 / ssum;
    }
    __syncthreads();
    // ---- c_t = alpha . enc ----
    int g = tid >> 8, t2 = tid & 255;
    const float* eb = enc + (size_t)b * SS * EE;
    float4 a4 = make_float4(0.f, 0.f, 0.f, 0.f);
    for (int s = g * 32; s < g * 32 + 32; ++s) {
        float al = sc[s];
        float4 e = *(const float4*)(eb + (size_t)s * 1024 + t2 * 4);
        a4.x = fmaf(al, e.x, a4.x); a4.y = fmaf(al, e.y, a4.y);
        a4.z = fmaf(al, e.z, a4.z); a4.w = fmaf(al, e.w, a4.w);
    }
    if (g) red[g - 1][t2] = a4;
    __syncthreads();
    if (g == 0) {
        float4 r1 = red[0][t2], r2 = red[1][t2], r3 = red[2][t2];
        a4.x += r1.x + r2.x + r3.x; a4.y += r1.y + r2.y + r3.y;
        a4.z += r1.z + r2.z + r3.z; a4.w += r1.w + r2.w + r3.w;
        *(float4*)(hc + (size_t)b * 2048 + 1024 + t2 * 4) = a4;
    }
}

// fallback LSTM pointwise (no keys workspace)
__global__ void k_lstm(const float* __restrict__ part, const float* __restrict__ bias,
                       float* __restrict__ h, float* __restrict__ c, float* __restrict__ hc)
{
    int idx = blockIdx.x * 256 + threadIdx.x;
    int b = idx >> 10, j = idx & 1023;
    size_t base = (size_t)b * 4096;
    float gi = bias[j], gf = bias[j + 1024], gg = bias[j + 2048], go = bias[j + 3072];
    #pragma unroll
    for (int p = 0; p < 12; ++p) {
        const float* pp = part + (size_t)p * 262144 + base;
        gi += pp[j]; gf += pp[j + 1024]; gg += pp[j + 2048]; go += pp[j + 3072];
    }
    float si = 1.f / (1.f + expf(-gi));
    float sf = 1.f / (1.f + expf(-gf));
    float so = 1.f / (1.f + expf(-go));
    float cn = sf * c[idx] + si * tanhf(gg);
    float hn = so * tanhf(cn);
    c[idx] = cn;
    h[idx] = hn;
    hc[(size_t)b * 2048 + j] = hn;
}

// fallback attention (qpart path)
__global__ __launch_bounds__(256) void k_attn_fb(const float* __restrict__ qpart,
                                                 const float* __restrict__ enc,
                                                 const int* __restrict__ enc_len,
                                                 float* __restrict__ hc)
{
    __shared__ float qs[1024];
    __shared__ float sc[128];
    int b = blockIdx.x, tid = threadIdx.x;
    for (int e = tid; e < 1024; e += 256) {
        size_t o = (size_t)b * 1024 + e;
        qs[e] = qpart[o] + qpart[o + 65536] + qpart[o + 131072] + qpart[o + 196608];
    }
    __syncthreads();
    int lane = tid & 63, w = tid >> 6;
    const float* eb = enc + (size_t)b * SS * EE;
    for (int s = w; s < 128; s += 4) {
        const float* er = eb + (size_t)s * 1024;
        float acc = 0.f;
        #pragma unroll
        for (int i = 0; i < 16; ++i) acc = fmaf(er[i * 64 + lane], qs[i * 64 + lane], acc);
        #pragma unroll
        for (int off = 32; off; off >>= 1) acc += __shfl_xor(acc, off, 64);
        if (lane == 0) sc[s] = acc;
    }
    __syncthreads();
    int len = enc_len[b];
    if (tid < 64) {
        float a  = (tid < len)      ? sc[tid]      : -1e9f;
        float a2 = (tid + 64 < len) ? sc[tid + 64] : -1e9f;
        float m = fmaxf(a, a2);
        #pragma unroll
        for (int off = 32; off; off >>= 1) m = fmaxf(m, __shfl_xor(m, off, 64));
        float ea = expf(a - m), ea2 = expf(a2 - m);
        float ssum = ea + ea2;
        #pragma unroll
        for (int off = 32; off; off >>= 1) ssum += __shfl_xor(ssum, off, 64);
        sc[tid] = ea / ssum; sc[tid + 64] = ea2 / ssum;
    }
    __syncthreads();
    float acc[4] = {0.f, 0.f, 0.f, 0.f};
    for (int s = 0; s < 128; ++s) {
        float al = sc[s];
        const float* er = eb + (size_t)s * 1024;
        #pragma unroll
        for (int j = 0; j < 4; ++j) acc[j] = fmaf(al, er[tid + j * 256], acc[j]);
    }
    #pragma unroll
    for (int j = 0; j < 4; ++j) hc[(size_t)b * 2048 + 1024 + tid + j * 256] = acc[j];
}

__global__ void k_reduce_dec(const float* __restrict__ part, float* __restrict__ dec)
{
    int i = blockIdx.x * 256 + threadIdx.x;   // 8192 float4s
    float4 s = ((const float4*)part)[i];
    #pragma unroll
    for (int p = 1; p < 16; ++p) {
        float4 v = ((const float4*)part)[p * 8192 + i];
        s.x += v.x; s.y += v.y; s.z += v.z; s.w += v.w;
    }
    ((float4*)dec)[i] = s;
}

// vocab logits GEMM (64 x 32000, K=512), 64x128 tiles, 4x8 micro.
// epilogue: per-tile row max+argmin-index AND per-tile sum(exp(x - tilemax))
__global__ __launch_bounds__(256) void k_vocab(const float* __restrict__ A,
                                               const float* __restrict__ B,
                                               float* __restrict__ out, int t,
                                               float* __restrict__ tval, int* __restrict__ tidx,
                                               float* __restrict__ tsum)
{
    __shared__ __attribute__((aligned(16))) float As[32][68];
    __shared__ __attribute__((aligned(16))) float Bs[32][136];
    int n0 = blockIdx.x << 7;
    const float* Bp = B + (size_t)n0 * EMBD;
    int tid = threadIdx.x;
    int tx = tid & 15, ty = tid >> 4;
    float acc[4][8] = {};
    int ar = tid >> 2, ak = (tid & 3) << 3;   // A stage: 64 rows x 8 floats
    int br = tid >> 1, bk = (tid & 1) << 4;   // B stage: 128 rows x 16 floats

    for (int kc = 0; kc < EMBD; kc += 32) {
        float4 a0 = *(const float4*)(A + (size_t)ar * EMBD + kc + ak);
        float4 a1 = *(const float4*)(A + (size_t)ar * EMBD + kc + ak + 4);
        As[ak+0][ar]=a0.x; As[ak+1][ar]=a0.y; As[ak+2][ar]=a0.z; As[ak+3][ar]=a0.w;
        As[ak+4][ar]=a1.x; As[ak+5][ar]=a1.y; As[ak+6][ar]=a1.z; As[ak+7][ar]=a1.w;
        const float* Brow = Bp + (size_t)br * EMBD + kc + bk;
        float4 b0 = *(const float4*)(Brow);
        float4 b1 = *(const float4*)(Brow + 4);
        float4 b2 = *(const float4*)(Brow + 8);
        float4 b3 = *(const float4*)(Brow + 12);
        Bs[bk+ 0][br]=b0.x; Bs[bk+ 1][br]=b0.y; Bs[bk+ 2][br]=b0.z; Bs[bk+ 3][br]=b0.w;
        Bs[bk+ 4][br]=b1.x; Bs[bk+ 5][br]=b1.y; Bs[bk+ 6][br]=b1.z; Bs[bk+ 7][br]=b1.w;
        Bs[bk+ 8][br]=b2.x; Bs[bk+ 9][br]=b2.y; Bs[bk+10][br]=b2.z; Bs[bk+11][br]=b2.w;
        Bs[bk+12][br]=b3.x; Bs[bk+13][br]=b3.y; Bs[bk+14][br]=b3.z; Bs[bk+15][br]=b3.w;
        __syncthreads();
        #pragma unroll 8
        for (int k = 0; k < 32; ++k) {
            float4 av  = *(const float4*)&As[k][ty << 2];
            float4 bv0 = *(const float4*)&Bs[k][tx << 2];
            float4 bv1 = *(const float4*)&Bs[k][64 + (tx << 2)];
            float am[4] = {av.x, av.y, av.z, av.w};
            float bm[8] = {bv0.x,bv0.y,bv0.z,bv0.w, bv1.x,bv1.y,bv1.z,bv1.w};
            #pragma unroll
            for (int i = 0; i < 4; ++i)
                #pragma unroll
                for (int j = 0; j < 8; ++j)
                    acc[i][j] = fmaf(am[i], bm[j], acc[i][j]);
        }
        __syncthreads();
    }
    size_t ldc = (size_t)TT * VV;
    float* Cb = out + (size_t)t * VV + n0;
    #pragma unroll
    for (int i = 0; i < 4; ++i) {
        float* Cr = Cb + (size_t)((ty << 2) + i) * ldc;
        *(float4*)(Cr + (tx << 2))      = make_float4(acc[i][0], acc[i][1], acc[i][2], acc[i][3]);
        *(float4*)(Cr + 64 + (tx << 2)) = make_float4(acc[i][4], acc[i][5], acc[i][6], acc[i][7]);
    }
    // epilogue
    #pragma unroll
    for (int i = 0; i < 4; ++i) {
        float v = acc[i][0]; int jx = 0;
        #pragma unroll
        for (int j = 1; j < 8; ++j) if (acc[i][j] > v) { v = acc[i][j]; jx = j; }
        int gi = n0 + ((jx < 4) ? (tx << 2) + jx : 64 + (tx << 2) + (jx - 4));
        #pragma unroll
        for (int mk = 1; mk < 16; mk <<= 1) {
            float ov = __shfl_xor(v, mk, 64);
            int   oi = __shfl_xor(gi, mk, 64);
            if (ov > v || (ov == v && oi < gi)) { v = ov; gi = oi; }
        }
        float s = 0.f;
        #pragma unroll
        for (int j = 0; j < 8; ++j) s += expf(acc[i][j] - v);
        #pragma unroll
        for (int mk = 1; mk < 16; mk <<= 1) s += __shfl_xor(s, mk, 64);
        if (tx == 0) {
            int row = (ty << 2) + i;
            tval[blockIdx.x * 64 + row] = v;
            tidx[blockIdx.x * 64 + row] = gi;
            tsum[blockIdx.x * 64 + row] = s;
        }
    }
}

// reduce tile maxima/sums per batch row: argmax, LSE, prev embedding, tl
__global__ __launch_bounds__(256) void k_argmax2(const float* __restrict__ tval,
                                                 const int* __restrict__ tidx,
                                                 const float* __restrict__ tsum,
                                                 const float* __restrict__ emb,
                                                 float* __restrict__ prev,
                                                 int* __restrict__ sym, int* __restrict__ tl,
                                                 float* __restrict__ lse, int t)
{
    __shared__ float bv[256];
    __shared__ int   bi[256];
    __shared__ float bs[256];
    int b = blockIdx.x, tid = threadIdx.x;
    float mv = -INFINITY; int mi = 0x7fffffff;
    if (tid < NTILE) { mv = tval[tid * 64 + b]; mi = tidx[tid * 64 + b]; }
    bv[tid] = mv; bi[tid] = mi;
    __syncthreads();
    for (int s = 128; s; s >>= 1) {
        if (tid < s) {
            float ov = bv[tid + s]; int oi = bi[tid + s];
            if (ov > bv[tid] || (ov == bv[tid] && oi < bi[tid])) { bv[tid] = ov; bi[tid] = oi; }
        }
        __syncthreads();
    }
    float M = bv[0];
    int best = bi[0];
    __syncthreads();
    float ps = 0.f;
    if (tid < NTILE) ps = tsum[tid * 64 + b] * expf(tval[tid * 64 + b] - M);
    bs[tid] = ps;
    __syncthreads();
    for (int s = 128; s; s >>= 1) {
        if (tid < s) bs[tid] += bs[tid + s];
        __syncthreads();
    }
    if (tid == 0) {
        sym[b] = best;
        if (best == 1) tl[b] = t + 1;
        lse[b * TT + t] = M + logf(bs[0]);
    }
    for (int e = tid; e < 128; e += 256)
        ((float4*)(prev + (size_t)b * EMBD))[e] = ((const float4*)(emb + (size_t)best * EMBD))[e];
}

__global__ void k_tl(const int* __restrict__ sym, const int* __restrict__ tl, float* __restrict__ out_tl)
{
    int b = threadIdx.x;
    out_tl[b] = (float)((sym[b] == 1) ? tl[b] : TT);
}

// final: single subtract pass using precomputed LSE
__global__ __launch_bounds__(256) void k_logsm_sub(float* __restrict__ out, const float* __restrict__ lse)
{
    float l = lse[blockIdx.x];
    float4* o4 = (float4*)(out + (size_t)blockIdx.x * VV);
    for (int v = threadIdx.x; v < 8000; v += 256) {
        float4 x = o4[v];
        x.x -= l; x.y -= l; x.z -= l; x.w -= l;
        o4[v] = x;
    }
}

__global__ void k_init(const float* __restrict__ dis, float* __restrict__ h, float* __restrict__ c,
                       float* __restrict__ prev, int* __restrict__ tl)
{
    int idx = blockIdx.x * 256 + threadIdx.x;   // 65536
    h[idx] = dis[idx];
    c[idx] = dis[65536 + idx];
    if (idx < 32768) prev[idx] = 0.f;
    if (idx < 64) tl[idx] = 0;
}

extern "C" void kernel_launch(void* const* d_in, const int* in_sizes, int n_in,
                              void* d_out, int out_size, void* d_ws, size_t ws_size,
                              hipStream_t stream)
{
    const float* dis  = (const float*)d_in[0];
    const float* enc  = (const float*)d_in[1];
    const int*   elen = (const int*)  d_in[2];
    const float* Wih  = (const float*)d_in[4];
    const float* Whh  = (const float*)d_in[5];
    const float* bl   = (const float*)d_in[6];
    const float* Wap  = (const float*)d_in[7];
    const float* Wout = (const float*)d_in[8];
    const float* Wvoc = (const float*)d_in[9];
    const float* emb  = (const float*)d_in[10];
    float* out = (float*)d_out;
    float* ws  = (float*)d_ws;

    float* h     = ws + OFF_H;
    float* c     = ws + OFF_C;
    float* prev  = ws + OFF_PREV;
    float* hc    = ws + OFF_HC;
    float* gpart = ws + OFF_GPART;
    float* dpart = ws + OFF_DPART;
    float* dec   = ws + OFF_DEC;
    float* qpart = ws + OFF_QPART;
    float* tval  = ws + OFF_TVAL;
    int*   tidx  = (int*)(ws + OFF_TIDX);
    float* tsum  = ws + OFF_TSUM;
    float* lse   = ws + OFF_LSE;
    int*   sym   = (int*)(ws + OFF_SYM);
    int*   tl    = (int*)(ws + OFF_TL);
    float* keys  = ws + OFF_KEYS;

    const bool use_keys = ws_size >= WS_NEED_KEYS;

    k_init<<<256, 256, 0, stream>>>(dis, h, c, prev, tl);
    if (use_keys)
        k_keys<<<dim3(8, 64), 256, 0, stream>>>(enc, Wap, keys);

    for (int t = 0; t < TT; ++t) {
        k_gates<<<dim3(64, 12), 256, 0, stream>>>(prev, h, Wih, Whh, gpart);
        if (use_keys) {
            k_lstm_attn<<<64, 1024, 0, stream>>>(gpart, bl, keys, enc, elen, h, c, hc);
        } else {
            k_lstm<<<256, 256, 0, stream>>>(gpart, bl, h, c, hc);
            k_gemm_bn<<<dim3(16, 4), 256, 0, stream>>>(h, HH, Wap, EE, qpart, EE, 256, 65536);
            k_attn_fb<<<64, 256, 0, stream>>>(qpart, enc, elen, hc);
        }
        k_gemm_bt<<<dim3(8, 16), 256, 0, stream>>>(hc, 2048, Wout, 2048, dpart, 512, 128, 32768);
        k_reduce_dec<<<32, 256, 0, stream>>>(dpart, dec);
        k_vocab<<<NTILE, 256, 0, stream>>>(dec, Wvoc, out, t, tval, tidx, tsum);
        k_argmax2<<<64, 256, 0, stream>>>(tval, tidx, tsum, emb, prev, sym, tl, lse, t);
    }

    k_tl<<<1, 64, 0, stream>>>(sym, tl, out + (size_t)BB * TT * VV);
    k_logsm_sub<<<3200, 256, 0, stream>>>(out, lse);
}